// Round 7
// baseline (281.134 us; speedup 1.0000x reference)
//
#include <hip/hip_runtime.h>
#include <cfloat>
#include <cstdint>

#define B_DIM 4
#define L_DIM 2048
#define NROW (B_DIM * L_DIM)      // 8192
#define TOPK 30
#define NEDGE (NROW * TOPK)       // 245760

// workspace layout (float offsets)
#define WS_CB    0                // 24576 floats: Cb[row][3]
#define WS_CX    24576            // 8192
#define WS_CY    32768            // 8192
#define WS_CZ    40960            // 8192
#define WS_TPOS  49152            // 8448:  Tpos[d][f], 66x128 fp32
#define WS_BPACK 57600            // 16384 floats = 32768 bf16, fragment-linear
#define WS_EIDX  73984            // 245760 ints

typedef __bf16 bf16x8 __attribute__((ext_vector_type(8)));
typedef __bf16 bf16x2 __attribute__((ext_vector_type(2)));
typedef float f32x4 __attribute__((ext_vector_type(4)));

static __device__ __forceinline__ unsigned short f2bf(float x) {
  unsigned u = __float_as_uint(x);
  unsigned r = (u + 0x7fffu + ((u >> 16) & 1u)) >> 16;
  return (unsigned short)r;
}

static __device__ __forceinline__ unsigned pk_bf16(float a, float b) {
#if __has_builtin(__builtin_amdgcn_cvt_pk_bf16_f32)
  union { bf16x2 v; unsigned u; } cv;
  cv.v = __builtin_amdgcn_cvt_pk_bf16_f32(a, b);
  return cv.u;
#else
  return (unsigned)f2bf(a) | ((unsigned)f2bf(b) << 16);
#endif
}

// ---------------------------------------------------------------- prep
__global__ void prep_kernel(const float* __restrict__ X,
                            const float* __restrict__ pe_w,
                            const float* __restrict__ pe_b,
                            const float* __restrict__ edge_w,
                            float* __restrict__ ws) {
  int tid = blockIdx.x * 256 + threadIdx.x;
  if (tid < NROW) {
    const float* Xr = X + (size_t)tid * 12;
    float nx = Xr[0], ny = Xr[1], nz = Xr[2];   // N
    float cx = Xr[3], cy = Xr[4], cz = Xr[5];   // C
    float ax = Xr[6], ay = Xr[7], az = Xr[8];   // Ca
    float bx = ax - nx, by = ay - ny, bz = az - nz;   // b = Ca - N
    float vx = cx - ax, vy = cy - ay, vz = cz - az;   // c = C - Ca
    float crx = by * vz - bz * vy;
    float cry = bz * vx - bx * vz;
    float crz = bx * vy - by * vx;
    ws[WS_CB + tid * 3 + 0] = -0.58273431f * crx + 0.56802827f * bx - 0.54067466f * vx + ax;
    ws[WS_CB + tid * 3 + 1] = -0.58273431f * cry + 0.56802827f * by - 0.54067466f * vy + ay;
    ws[WS_CB + tid * 3 + 2] = -0.58273431f * crz + 0.56802827f * bz - 0.54067466f * vz + az;
    ws[WS_CX + tid] = cx;
    ws[WS_CY + tid] = cy;
    ws[WS_CZ + tid] = cz;
  } else if (tid < NROW + 8448) {
    int t2 = tid - NROW;
    int d = t2 >> 7, f = t2 & 127;
    float s = 0.f;
    #pragma unroll
    for (int n = 0; n < 16; n++)
      s += edge_w[f * 272 + n] * (pe_w[n * 66 + d] + pe_b[n]);
    ws[WS_TPOS + t2] = s;
  } else if (tid < NROW + 8448 + 16384) {
    // Bpack: bf16 fragment-linear [c(4)][nt(8)][s(2)][lane(64)][j(8)] as u32 pairs
    int i2 = tid - NROW - 8448;
    int j2 = i2 & 3;
    int lane = (i2 >> 2) & 63;
    int s = (i2 >> 8) & 1;
    int nt = (i2 >> 9) & 7;
    int c = (i2 >> 12) & 3;
    int f = nt * 16 + (lane & 15);
    int k = c * 64 + s * 32 + (lane >> 4) * 8 + j2 * 2;
    float v0 = edge_w[f * 272 + 16 + k];
    float v1 = edge_w[f * 272 + 16 + k + 1];
    unsigned out = (unsigned)f2bf(v0) | ((unsigned)f2bf(v1) << 16);
    ((unsigned*)(ws + WS_BPACK))[i2] = out;
  }
}

// ---------------------------------------------------------------- top-k
// v7: round-2-verified tournament (4 waves x 512, sorted-8 queue, ballot
// winner resolution, LDS spill queue, 4-run bitonic merge) with ONE
// scheduling tweak: the next queue head is held in a register (nxt), so
// a pop is a register move; the LDS refill for the entry after it issues
// immediately and its ~120cy latency hides until this lane's next win
// (earliest: next iteration). Queue semantics identical to round 2.
#define CAS64(a, b) { bool lt = (a) < (b); \
  unsigned long long lo = lt ? (a) : (b), hi = lt ? (b) : (a); (a) = lo; (b) = hi; }

__global__ void __launch_bounds__(256)
topk_kernel(const float* __restrict__ ws,
            const float* __restrict__ mask,
            int* __restrict__ eidx_out,
            float* __restrict__ idxf_out) {
  int row = blockIdx.x;
  int b = row >> 11;
  int li = row & 2047;
  int t = threadIdx.x;
  int lane = t & 63;
  int w = t >> 6;                  // wave 0..3, 512 elements each

  __shared__ float s_red[4];
  __shared__ unsigned long long s_cand[128];       // 4 runs x 32
  __shared__ unsigned long long s_q[4 * 6 * 64];   // per-wave spill: slots 2..7

  const float* Cx = ws + WS_CX + b * L_DIM;
  const float* Cy = ws + WS_CY + b * L_DIM;
  const float* Cz = ws + WS_CZ + b * L_DIM;

  float cix = Cx[li], ciy = Cy[li], ciz = Cz[li];
  float mi = mask[row];

  float dloc[8], m2l[8];
  float dmax = 0.f;
  #pragma unroll
  for (int i = 0; i < 8; i++) {
    int j = w * 512 + i * 64 + lane;
    float dx = Cx[j] - cix;
    float dy = Cy[j] - ciy;
    float dz = Cz[j] - ciz;
    float raw = sqrtf(dx * dx + dy * dy + dz * dz + 1e-6f);
    float m2 = mi * mask[b * L_DIM + j];
    float d = m2 * raw;
    dloc[i] = d;
    m2l[i] = m2;
    dmax = fmaxf(dmax, d);
  }
  #pragma unroll
  for (int off = 32; off; off >>= 1)
    dmax = fmaxf(dmax, __shfl_xor(dmax, off));
  if (lane == 0) s_red[w] = dmax;
  __syncthreads();
  dmax = fmaxf(fmaxf(s_red[0], s_red[1]), fmaxf(s_red[2], s_red[3]));

  unsigned long long key[8];
  #pragma unroll
  for (int i = 0; i < 8; i++) {
    float v = dloc[i] + (1.f - m2l[i]) * dmax;
    int j = w * 512 + i * 64 + lane;
    key[i] = ((unsigned long long)__float_as_uint(v) << 32) | (unsigned)j;
  }
  // sort 8 keys ascending (19-comparator network)
  CAS64(key[0], key[1]); CAS64(key[2], key[3]); CAS64(key[4], key[5]); CAS64(key[6], key[7]);
  CAS64(key[0], key[2]); CAS64(key[1], key[3]); CAS64(key[4], key[6]); CAS64(key[5], key[7]);
  CAS64(key[1], key[2]); CAS64(key[5], key[6]); CAS64(key[0], key[4]); CAS64(key[3], key[7]);
  CAS64(key[1], key[5]); CAS64(key[2], key[6]);
  CAS64(key[1], key[4]); CAS64(key[3], key[6]);
  CAS64(key[2], key[4]); CAS64(key[3], key[5]);
  CAS64(key[3], key[4]);

  // spill slots 2..7 to the private LDS queue (slot-major: consecutive
  // lanes -> consecutive b64, 2-way bank aliasing = free). Only this
  // wave's lanes read these entries back, so no barrier is needed.
  #pragma unroll
  for (int s = 2; s < 8; s++)
    s_q[(w * 6 + (s - 2)) * 64 + lane] = key[s];

  unsigned cv = (unsigned)(key[0] >> 32);
  unsigned cj = (unsigned)key[0];
  unsigned long long nxt = key[1];   // next head, in-register
  int ptr = 0;                       // next spill slot (0..5), >=6 exhausted

  if (lane >= TOPK && lane < 32) s_cand[w * 32 + lane] = ~0ull;

  for (int n = 0; n < TOPK; n++) {
    // wave-wide min of head values
    unsigned mv = cv;
    #pragma unroll
    for (int off = 32; off; off >>= 1) {
      unsigned o = __shfl_xor(mv, off);
      mv = o < mv ? o : mv;
    }
    unsigned long long ball = __ballot(cv == mv);
    unsigned wj;
    bool me;
    if (__popcll(ball) == 1) {     // unique winner (uniform branch, ~always)
      int wl = (int)__builtin_ctzll(ball);
      wj = (unsigned)__shfl((int)cj, wl);
      me = (lane == wl);
    } else {                       // exact tie-break: min index among tied
      unsigned tj = (cv == mv) ? cj : 0xffffffffu;
      unsigned mj = tj;
      #pragma unroll
      for (int off = 32; off; off >>= 1) {
        unsigned o = __shfl_xor(mj, off);
        mj = o < mj ? o : mj;
      }
      wj = mj;
      me = (cv == mv) && (cj == mj);
    }
    if (lane == n)
      s_cand[w * 32 + n] = ((unsigned long long)mv << 32) | wj;
    if (me) {                      // pop: head <- nxt (register), refill nxt
      cv = (unsigned)(nxt >> 32);
      cj = (unsigned)nxt;
      nxt = (ptr < 6) ? s_q[(w * 6 + ptr) * 64 + lane] : ~0ull;
      ptr++;
    }
  }
  __syncthreads();

  // wave 0: merge 4 sorted-32 runs via truncated bitonic merges
  if (w == 0) {
    unsigned long long c0 = s_cand[lane];
    unsigned long long c1 = s_cand[64 + lane];
    bool lowhalf = lane < 32;

    #define MERGE32(c) { \
      unsigned long long p = __shfl_xor((c), 63); \
      (c) = (c) < p ? (c) : p; \
      _Pragma("unroll") \
      for (int j = 16; j; j >>= 1) { \
        unsigned long long q = __shfl_xor((c), j); \
        bool up = (lane & j) == 0; \
        unsigned long long mn = (c) < q ? (c) : q; \
        unsigned long long mx = (c) < q ? q : (c); \
        (c) = up ? mn : mx; \
      } }

    MERGE32(c0); MERGE32(c1);
    c0 = lowhalf ? c0 : c1;
    MERGE32(c0);
    #undef MERGE32

    if (lane < TOPK) {
      int j = (int)(c0 & 0xffffffffull);
      eidx_out[row * TOPK + lane] = j;
      idxf_out[row * TOPK + lane] = (float)j;
    }
  }
}

// ---------------------------------------------------------------- edges
// atom-pair codes, 4 bits each, p=0..15 (0=N,1=C,2=Ca,3=Cb)
#define PA_BITS 0x2323203001113201ull
#define PB_BITS 0x3001112323203201ull

// smem layout (bytes): DIST 64x17 fp32 [0,4352) | A [4352,12544) |
//                      B [12544,28928) | POS [28928,29184)
#define SM_DIST 0
#define SM_A    4352
#define SM_B    12544
#define SM_POS  28928
#define SM_TOTAL 29184

__global__ void __launch_bounds__(256)
edge_kernel(const float* __restrict__ X,
            const float* __restrict__ ws,
            const int* __restrict__ ridx,
            const int* __restrict__ chain,
            const float* __restrict__ ln_g,
            const float* __restrict__ ln_b,
            float* __restrict__ out) {
  __shared__ __align__(16) char smem[SM_TOTAL];
  float* s_dist = (float*)(smem + SM_DIST);   // [e][17], p in 0..15
  int* s_pos = (int*)(smem + SM_POS);

  int t = threadIdx.x;
  int r0 = blockIdx.x * 2;
  const float* Cbw = ws + WS_CB;
  const float* Tpos = ws + WS_TPOS;
  const int* eidx = (const int*)(ws + WS_EIDX);

  // phase 0: per-edge distances + positional index (4 threads per edge)
  if (t < 240) {
    int e = t >> 2, q = t & 3;
    int row = r0 + (e >= 30 ? 1 : 0);
    int kn = e - (e >= 30 ? 30 : 0);
    int bb = row >> 11;
    int j = eidx[row * TOPK + kn];
    int jrow = bb * L_DIM + j;
    if (q == 0) {
      int off = ridx[row] - ridx[jrow];
      int same = (chain[row] == chain[jrow]);
      s_pos[e] = same ? min(max(off + 32, 0), 64) : 65;
    }
    const float4* Xi4 = (const float4*)(X + (size_t)row * 12);
    const float4* Xj4 = (const float4*)(X + (size_t)jrow * 12);
    float4 i0 = Xi4[0], i1 = Xi4[1];
    float4 j0 = Xj4[0], j1 = Xj4[1];
    float i2x = X[(size_t)row * 12 + 8];
    float j2x = X[(size_t)jrow * 12 + 8];
    float axi[4], ayi[4], azi[4], axj[4], ayj[4], azj[4];
    axi[0] = i0.x; ayi[0] = i0.y; azi[0] = i0.z;        // N
    axi[1] = i0.w; ayi[1] = i1.x; azi[1] = i1.y;        // C
    axi[2] = i1.z; ayi[2] = i1.w; azi[2] = i2x;         // Ca
    axi[3] = Cbw[row * 3 + 0]; ayi[3] = Cbw[row * 3 + 1]; azi[3] = Cbw[row * 3 + 2];
    axj[0] = j0.x; ayj[0] = j0.y; azj[0] = j0.z;
    axj[1] = j0.w; ayj[1] = j1.x; azj[1] = j1.y;
    axj[2] = j1.z; ayj[2] = j1.w; azj[2] = j2x;
    axj[3] = Cbw[jrow * 3 + 0]; ayj[3] = Cbw[jrow * 3 + 1]; azj[3] = Cbw[jrow * 3 + 2];
    #pragma unroll
    for (int u = 0; u < 4; u++) {
      int p = q * 4 + u;
      int a = (int)((PA_BITS >> (p * 4)) & 7);
      int bc = (int)((PB_BITS >> (p * 4)) & 7);
      float dx = axi[a] - axj[bc];
      float dy = ayi[a] - ayj[bc];
      float dz = azi[a] - azj[bc];
      s_dist[e * 17 + p] = sqrtf(dx * dx + dy * dy + dz * dz + 1e-6f);
    }
  } else {
    int t2 = t - 240;        // pad edges 60..63
    int e = 60 + (t2 >> 2), q = t2 & 3;
    if (q == 0) s_pos[e] = 0;
    #pragma unroll
    for (int u = 0; u < 4; u++) s_dist[e * 17 + q * 4 + u] = 8.0f;
  }
  __syncthreads();

  int lane = t & 63;
  int w = t >> 6;

  f32x4 zero4 = {0.f, 0.f, 0.f, 0.f};
  f32x4 acc[8];
  #pragma unroll
  for (int nt = 0; nt < 8; nt++) acc[nt] = zero4;

  // RBF constants: exp(-((d-mu_r)/1.25)^2) = exp2(-(d*C1 - (2+r*4/3)*C1)^2)
  // with C1 = 0.8*sqrt(log2 e)
  const float C1 = 0.96089792702916f;        // 0.8 * 1.2011224087864498
  const float DC = 1.28119723603888f;        // (4/3) * C1
  const float B0 = -1.92179585405832f;       // -2 * C1

  for (int c = 0; c < 4; c++) {
    // stage B chunk (16 KB) fragment-linear from global
    {
      const float4* src = (const float4*)(ws + WS_BPACK) + c * 1024;
      float4* dst = (float4*)(smem + SM_B);
      #pragma unroll
      for (int v = 0; v < 4; v++) dst[t + v * 256] = src[t + v * 256];
    }
    // fill A fragment-linear: [w(4)][s(2)][lane(64)][j(8)] bf16, as u32 pairs
    {
      unsigned* ap = (unsigned*)(smem + SM_A);
      #pragma unroll
      for (int v = 0; v < 8; v++) {
        int i2 = t + v * 256;
        int j2 = i2 & 3;
        int al = (i2 >> 2) & 63;
        int s = (i2 >> 8) & 1;
        int aw = (i2 >> 9) & 3;
        int m = aw * 16 + (al & 15);
        int k = c * 64 + s * 32 + (al >> 4) * 8 + j2 * 2;
        float d = s_dist[m * 17 + (k >> 4)];
        float rrf = (float)(k & 15);
        float base = fmaf(rrf, -DC, B0);
        float zs0 = fmaf(d, C1, base);
        float zs1 = zs0 - DC;
        float v0 = __builtin_exp2f(-zs0 * zs0);
        float v1 = __builtin_exp2f(-zs1 * zs1);
        ap[i2] = pk_bf16(v0, v1);
      }
    }
    __syncthreads();
    // MFMA: 2 k-steps x 8 n-tiles
    #pragma unroll
    for (int s = 0; s < 2; s++) {
      bf16x8 a = *(const bf16x8*)(smem + SM_A + ((w * 2 + s) * 64 + lane) * 16);
      #pragma unroll
      for (int nt = 0; nt < 8; nt++) {
        bf16x8 bfr = *(const bf16x8*)(smem + SM_B + ((nt * 2 + s) * 64 + lane) * 16);
        acc[nt] = __builtin_amdgcn_mfma_f32_16x16x32_bf16(a, bfr, acc[nt], 0, 0, 0);
      }
    }
    __syncthreads();
  }

  // epilogue: LN directly from accumulator layout.
  // acc[nt][r] = C[m][f], m = w*16 + quad*4 + r, f = nt*16 + col0
  int quad = lane >> 4;
  int col0 = lane & 15;
  #pragma unroll
  for (int r = 0; r < 4; r++) {
    int e = w * 16 + quad * 4 + r;
    bool live = (e < 60);
    int dp = live ? s_pos[e] : 0;
    const float* tp = Tpos + dp * 128;
    float vv[8];
    float s = 0.f, s2 = 0.f;
    #pragma unroll
    for (int nt = 0; nt < 8; nt++) {
      float x = acc[nt][r] + tp[nt * 16 + col0];
      vv[nt] = x;
      s += x;
      s2 += x * x;
    }
    #pragma unroll
    for (int off = 8; off; off >>= 1) {
      s += __shfl_xor(s, off, 16);
      s2 += __shfl_xor(s2, off, 16);
    }
    float mu = s * (1.0f / 128.0f);
    float var = s2 * (1.0f / 128.0f) - mu * mu;
    float inv = rsqrtf(var + 1e-5f);
    if (live) {
      int row = r0 + (e >= 30 ? 1 : 0);
      int kn = e - (e >= 30 ? 30 : 0);
      float* o = out + ((size_t)row * TOPK + kn) * 128;
      #pragma unroll
      for (int nt = 0; nt < 8; nt++) {
        int f = nt * 16 + col0;
        o[f] = (vv[nt] - mu) * inv * ln_g[f] + ln_b[f];
      }
    }
  }
}

// ---------------------------------------------------------------- launch
extern "C" void kernel_launch(void* const* d_in, const int* in_sizes, int n_in,
                              void* d_out, int out_size, void* d_ws, size_t ws_size,
                              hipStream_t stream) {
  const float* X      = (const float*)d_in[0];
  const float* mask   = (const float*)d_in[1];
  const int*   ridx   = (const int*)d_in[2];
  const int*   chain  = (const int*)d_in[3];
  const float* pe_w   = (const float*)d_in[4];
  const float* pe_b   = (const float*)d_in[5];
  const float* edge_w = (const float*)d_in[6];
  const float* ln_g   = (const float*)d_in[7];
  const float* ln_b   = (const float*)d_in[8];
  float* out = (float*)d_out;
  float* ws  = (float*)d_ws;

  hipLaunchKernelGGL(prep_kernel, dim3(129), dim3(256), 0, stream,
                     X, pe_w, pe_b, edge_w, ws);
  hipLaunchKernelGGL(topk_kernel, dim3(NROW), dim3(256), 0, stream,
                     ws, mask, (int*)(ws + WS_EIDX), out + (size_t)NEDGE * 128);
  hipLaunchKernelGGL(edge_kernel, dim3(NROW / 2), dim3(256), 0, stream,
                     X, ws, ridx, chain, ln_g, ln_b, out);
}

// Round 8
// 248.610 us; speedup vs baseline: 1.1308x; 1.1308x over previous
//
#include <hip/hip_runtime.h>
#include <cfloat>
#include <cstdint>

#define B_DIM 4
#define L_DIM 2048
#define NROW (B_DIM * L_DIM)      // 8192
#define TOPK 30
#define NEDGE (NROW * TOPK)       // 245760

// workspace layout (float offsets)
#define WS_CB    0                // 24576 floats: Cb[row][3]
#define WS_CX    24576            // 8192
#define WS_CY    32768            // 8192
#define WS_CZ    40960            // 8192
#define WS_TPOS  49152            // 8448:  Tpos[d][f], 66x128 fp32
#define WS_BPACK 57600            // 16384 floats = 32768 bf16, fragment-linear
#define WS_EIDX  73984            // 245760 ints

typedef __bf16 bf16x8 __attribute__((ext_vector_type(8)));
typedef __bf16 bf16x2 __attribute__((ext_vector_type(2)));
typedef float f32x4 __attribute__((ext_vector_type(4)));

static __device__ __forceinline__ unsigned short f2bf(float x) {
  unsigned u = __float_as_uint(x);
  unsigned r = (u + 0x7fffu + ((u >> 16) & 1u)) >> 16;
  return (unsigned short)r;
}

static __device__ __forceinline__ unsigned pk_bf16(float a, float b) {
#if __has_builtin(__builtin_amdgcn_cvt_pk_bf16_f32)
  union { bf16x2 v; unsigned u; } cv;
  cv.v = __builtin_amdgcn_cvt_pk_bf16_f32(a, b);
  return cv.u;
#else
  return (unsigned)f2bf(a) | ((unsigned)f2bf(b) << 16);
#endif
}

// Wave64 u32 min-reduce on the VALU only (no DS pipe): DPP row_shr
// 1,2,4,8 then row_bcast15 (rows 1,3) and row_bcast31 (rows 2,3);
// full reduction lands in lane 63, broadcast back via v_readlane.
// For MIN, invalid-source lanes returning old(=v) are the identity.
static __device__ __forceinline__ unsigned wave_min_u32_dpp(unsigned v) {
#if __has_builtin(__builtin_amdgcn_update_dpp) && __has_builtin(__builtin_amdgcn_readlane)
  int x = (int)v, t;
  t = __builtin_amdgcn_update_dpp(x, x, 0x111, 0xf, 0xf, false);  // row_shr:1
  x = ((unsigned)t < (unsigned)x) ? t : x;
  t = __builtin_amdgcn_update_dpp(x, x, 0x112, 0xf, 0xf, false);  // row_shr:2
  x = ((unsigned)t < (unsigned)x) ? t : x;
  t = __builtin_amdgcn_update_dpp(x, x, 0x114, 0xf, 0xf, false);  // row_shr:4
  x = ((unsigned)t < (unsigned)x) ? t : x;
  t = __builtin_amdgcn_update_dpp(x, x, 0x118, 0xf, 0xf, false);  // row_shr:8
  x = ((unsigned)t < (unsigned)x) ? t : x;
  t = __builtin_amdgcn_update_dpp(x, x, 0x142, 0xa, 0xf, false);  // row_bcast15
  x = ((unsigned)t < (unsigned)x) ? t : x;
  t = __builtin_amdgcn_update_dpp(x, x, 0x143, 0xc, 0xf, false);  // row_bcast31
  x = ((unsigned)t < (unsigned)x) ? t : x;
  return (unsigned)__builtin_amdgcn_readlane(x, 63);
#else
  unsigned mv = v;
  #pragma unroll
  for (int off = 32; off; off >>= 1) {
    unsigned o = __shfl_xor(mv, off);
    mv = o < mv ? o : mv;
  }
  return mv;
#endif
}

// ---------------------------------------------------------------- prep
__global__ void prep_kernel(const float* __restrict__ X,
                            const float* __restrict__ pe_w,
                            const float* __restrict__ pe_b,
                            const float* __restrict__ edge_w,
                            float* __restrict__ ws) {
  int tid = blockIdx.x * 256 + threadIdx.x;
  if (tid < NROW) {
    const float* Xr = X + (size_t)tid * 12;
    float nx = Xr[0], ny = Xr[1], nz = Xr[2];   // N
    float cx = Xr[3], cy = Xr[4], cz = Xr[5];   // C
    float ax = Xr[6], ay = Xr[7], az = Xr[8];   // Ca
    float bx = ax - nx, by = ay - ny, bz = az - nz;   // b = Ca - N
    float vx = cx - ax, vy = cy - ay, vz = cz - az;   // c = C - Ca
    float crx = by * vz - bz * vy;
    float cry = bz * vx - bx * vz;
    float crz = bx * vy - by * vx;
    ws[WS_CB + tid * 3 + 0] = -0.58273431f * crx + 0.56802827f * bx - 0.54067466f * vx + ax;
    ws[WS_CB + tid * 3 + 1] = -0.58273431f * cry + 0.56802827f * by - 0.54067466f * vy + ay;
    ws[WS_CB + tid * 3 + 2] = -0.58273431f * crz + 0.56802827f * bz - 0.54067466f * vz + az;
    ws[WS_CX + tid] = cx;
    ws[WS_CY + tid] = cy;
    ws[WS_CZ + tid] = cz;
  } else if (tid < NROW + 8448) {
    int t2 = tid - NROW;
    int d = t2 >> 7, f = t2 & 127;
    float s = 0.f;
    #pragma unroll
    for (int n = 0; n < 16; n++)
      s += edge_w[f * 272 + n] * (pe_w[n * 66 + d] + pe_b[n]);
    ws[WS_TPOS + t2] = s;
  } else if (tid < NROW + 8448 + 16384) {
    // Bpack: bf16 fragment-linear [c(4)][nt(8)][s(2)][lane(64)][j(8)] as u32 pairs
    int i2 = tid - NROW - 8448;
    int j2 = i2 & 3;
    int lane = (i2 >> 2) & 63;
    int s = (i2 >> 8) & 1;
    int nt = (i2 >> 9) & 7;
    int c = (i2 >> 12) & 3;
    int f = nt * 16 + (lane & 15);
    int k = c * 64 + s * 32 + (lane >> 4) * 8 + j2 * 2;
    float v0 = edge_w[f * 272 + 16 + k];
    float v1 = edge_w[f * 272 + 16 + k + 1];
    unsigned out = (unsigned)f2bf(v0) | ((unsigned)f2bf(v1) << 16);
    ((unsigned*)(ws + WS_BPACK))[i2] = out;
  }
}

// ---------------------------------------------------------------- top-k
// v8: round-7-verified tournament with the DS-pipe ops removed from the
// hot loop: DPP min-reduce (VALU only) + readlane broadcasts + result
// accumulated in a register (single s_cand write after the loop).
// Queue/tie-break/merge semantics identical to the verified v7.
#define CAS64(a, b) { bool lt = (a) < (b); \
  unsigned long long lo = lt ? (a) : (b), hi = lt ? (b) : (a); (a) = lo; (b) = hi; }

__global__ void __launch_bounds__(256)
topk_kernel(const float* __restrict__ ws,
            const float* __restrict__ mask,
            int* __restrict__ eidx_out,
            float* __restrict__ idxf_out) {
  int row = blockIdx.x;
  int b = row >> 11;
  int li = row & 2047;
  int t = threadIdx.x;
  int lane = t & 63;
  int w = t >> 6;                  // wave 0..3, 512 elements each

  __shared__ float s_red[4];
  __shared__ unsigned long long s_cand[128];       // 4 runs x 32
  __shared__ unsigned long long s_q[4 * 6 * 64];   // per-wave spill: slots 2..7

  const float* Cx = ws + WS_CX + b * L_DIM;
  const float* Cy = ws + WS_CY + b * L_DIM;
  const float* Cz = ws + WS_CZ + b * L_DIM;

  float cix = Cx[li], ciy = Cy[li], ciz = Cz[li];
  float mi = mask[row];

  float dloc[8], m2l[8];
  float dmax = 0.f;
  #pragma unroll
  for (int i = 0; i < 8; i++) {
    int j = w * 512 + i * 64 + lane;
    float dx = Cx[j] - cix;
    float dy = Cy[j] - ciy;
    float dz = Cz[j] - ciz;
    float raw = sqrtf(dx * dx + dy * dy + dz * dz + 1e-6f);
    float m2 = mi * mask[b * L_DIM + j];
    float d = m2 * raw;
    dloc[i] = d;
    m2l[i] = m2;
    dmax = fmaxf(dmax, d);
  }
  #pragma unroll
  for (int off = 32; off; off >>= 1)
    dmax = fmaxf(dmax, __shfl_xor(dmax, off));
  if (lane == 0) s_red[w] = dmax;
  __syncthreads();
  dmax = fmaxf(fmaxf(s_red[0], s_red[1]), fmaxf(s_red[2], s_red[3]));

  unsigned long long key[8];
  #pragma unroll
  for (int i = 0; i < 8; i++) {
    float v = dloc[i] + (1.f - m2l[i]) * dmax;
    int j = w * 512 + i * 64 + lane;
    key[i] = ((unsigned long long)__float_as_uint(v) << 32) | (unsigned)j;
  }
  // sort 8 keys ascending (19-comparator network)
  CAS64(key[0], key[1]); CAS64(key[2], key[3]); CAS64(key[4], key[5]); CAS64(key[6], key[7]);
  CAS64(key[0], key[2]); CAS64(key[1], key[3]); CAS64(key[4], key[6]); CAS64(key[5], key[7]);
  CAS64(key[1], key[2]); CAS64(key[5], key[6]); CAS64(key[0], key[4]); CAS64(key[3], key[7]);
  CAS64(key[1], key[5]); CAS64(key[2], key[6]);
  CAS64(key[1], key[4]); CAS64(key[3], key[6]);
  CAS64(key[2], key[4]); CAS64(key[3], key[5]);
  CAS64(key[3], key[4]);

  // spill slots 2..7 to the private LDS queue (slot-major: consecutive
  // lanes -> consecutive b64, 2-way bank aliasing = free). Only this
  // wave's lanes read these entries back, so no barrier is needed.
  #pragma unroll
  for (int s = 2; s < 8; s++)
    s_q[(w * 6 + (s - 2)) * 64 + lane] = key[s];

  unsigned cv = (unsigned)(key[0] >> 32);
  unsigned cj = (unsigned)key[0];
  unsigned long long nxt = key[1];   // next head, in-register
  int ptr = 0;                       // next spill slot (0..5), >=6 exhausted

  unsigned long long myout = ~0ull;

  for (int n = 0; n < TOPK; n++) {
    unsigned mv = wave_min_u32_dpp(cv);          // VALU-only reduce
    unsigned long long ball = __ballot(cv == mv);
    if (ball == 0) ball = 1;                     // unreachable if reduce ok
    unsigned wj;
    bool me;
    if (__popcll(ball) == 1) {     // unique winner (uniform branch, ~always)
      int wl = (int)__builtin_ctzll(ball);
#if __has_builtin(__builtin_amdgcn_readlane)
      wj = (unsigned)__builtin_amdgcn_readlane((int)cj, wl);
#else
      wj = (unsigned)__shfl((int)cj, wl);
#endif
      me = (lane == wl);
    } else {                       // exact tie-break: min index among tied
      unsigned tj = (cv == mv) ? cj : 0xffffffffu;
      unsigned mj = tj;
      #pragma unroll
      for (int off = 32; off; off >>= 1) {
        unsigned o = __shfl_xor(mj, off);
        mj = o < mj ? o : mj;
      }
      wj = mj;
      me = (cv == mv) && (cj == mj);
    }
    if (lane == n)
      myout = ((unsigned long long)mv << 32) | wj;
    if (me) {                      // pop: head <- nxt (register), refill nxt
      cv = (unsigned)(nxt >> 32);
      cj = (unsigned)nxt;
      nxt = (ptr < 6) ? s_q[(w * 6 + ptr) * 64 + lane] : ~0ull;
      ptr++;
    }
  }
  if (lane < 32)
    s_cand[w * 32 + lane] = (lane < TOPK) ? myout : ~0ull;
  __syncthreads();

  // wave 0: merge 4 sorted-32 runs via truncated bitonic merges
  if (w == 0) {
    unsigned long long c0 = s_cand[lane];
    unsigned long long c1 = s_cand[64 + lane];
    bool lowhalf = lane < 32;

    #define MERGE32(c) { \
      unsigned long long p = __shfl_xor((c), 63); \
      (c) = (c) < p ? (c) : p; \
      _Pragma("unroll") \
      for (int j = 16; j; j >>= 1) { \
        unsigned long long q = __shfl_xor((c), j); \
        bool up = (lane & j) == 0; \
        unsigned long long mn = (c) < q ? (c) : q; \
        unsigned long long mx = (c) < q ? q : (c); \
        (c) = up ? mn : mx; \
      } }

    MERGE32(c0); MERGE32(c1);
    c0 = lowhalf ? c0 : c1;
    MERGE32(c0);
    #undef MERGE32

    if (lane < TOPK) {
      int j = (int)(c0 & 0xffffffffull);
      eidx_out[row * TOPK + lane] = j;
      idxf_out[row * TOPK + lane] = (float)j;
    }
  }
}

// ---------------------------------------------------------------- edges
// atom-pair codes, 4 bits each, p=0..15 (0=N,1=C,2=Ca,3=Cb)
#define PA_BITS 0x2323203001113201ull
#define PB_BITS 0x3001112323203201ull

// smem layout (bytes): DIST 64x17 fp32 [0,4352) | A [4352,12544) |
//                      B [12544,28928) | POS [28928,29184)
#define SM_DIST 0
#define SM_A    4352
#define SM_B    12544
#define SM_POS  28928
#define SM_TOTAL 29184

__global__ void __launch_bounds__(256)
edge_kernel(const float* __restrict__ X,
            const float* __restrict__ ws,
            const int* __restrict__ ridx,
            const int* __restrict__ chain,
            const float* __restrict__ ln_g,
            const float* __restrict__ ln_b,
            float* __restrict__ out) {
  __shared__ __align__(16) char smem[SM_TOTAL];
  float* s_dist = (float*)(smem + SM_DIST);   // [e][17], p in 0..15
  int* s_pos = (int*)(smem + SM_POS);

  int t = threadIdx.x;
  int r0 = blockIdx.x * 2;
  const float* Cbw = ws + WS_CB;
  const float* Tpos = ws + WS_TPOS;
  const int* eidx = (const int*)(ws + WS_EIDX);

  // phase 0: per-edge distances + positional index (4 threads per edge)
  if (t < 240) {
    int e = t >> 2, q = t & 3;
    int row = r0 + (e >= 30 ? 1 : 0);
    int kn = e - (e >= 30 ? 30 : 0);
    int bb = row >> 11;
    int j = eidx[row * TOPK + kn];
    int jrow = bb * L_DIM + j;
    if (q == 0) {
      int off = ridx[row] - ridx[jrow];
      int same = (chain[row] == chain[jrow]);
      s_pos[e] = same ? min(max(off + 32, 0), 64) : 65;
    }
    const float4* Xi4 = (const float4*)(X + (size_t)row * 12);
    const float4* Xj4 = (const float4*)(X + (size_t)jrow * 12);
    float4 i0 = Xi4[0], i1 = Xi4[1];
    float4 j0 = Xj4[0], j1 = Xj4[1];
    float i2x = X[(size_t)row * 12 + 8];
    float j2x = X[(size_t)jrow * 12 + 8];
    float axi[4], ayi[4], azi[4], axj[4], ayj[4], azj[4];
    axi[0] = i0.x; ayi[0] = i0.y; azi[0] = i0.z;        // N
    axi[1] = i0.w; ayi[1] = i1.x; azi[1] = i1.y;        // C
    axi[2] = i1.z; ayi[2] = i1.w; azi[2] = i2x;         // Ca
    axi[3] = Cbw[row * 3 + 0]; ayi[3] = Cbw[row * 3 + 1]; azi[3] = Cbw[row * 3 + 2];
    axj[0] = j0.x; ayj[0] = j0.y; azj[0] = j0.z;
    axj[1] = j0.w; ayj[1] = j1.x; azj[1] = j1.y;
    axj[2] = j1.z; ayj[2] = j1.w; azj[2] = j2x;
    axj[3] = Cbw[jrow * 3 + 0]; ayj[3] = Cbw[jrow * 3 + 1]; azj[3] = Cbw[jrow * 3 + 2];
    #pragma unroll
    for (int u = 0; u < 4; u++) {
      int p = q * 4 + u;
      int a = (int)((PA_BITS >> (p * 4)) & 7);
      int bc = (int)((PB_BITS >> (p * 4)) & 7);
      float dx = axi[a] - axj[bc];
      float dy = ayi[a] - ayj[bc];
      float dz = azi[a] - azj[bc];
      s_dist[e * 17 + p] = sqrtf(dx * dx + dy * dy + dz * dz + 1e-6f);
    }
  } else {
    int t2 = t - 240;        // pad edges 60..63
    int e = 60 + (t2 >> 2), q = t2 & 3;
    if (q == 0) s_pos[e] = 0;
    #pragma unroll
    for (int u = 0; u < 4; u++) s_dist[e * 17 + q * 4 + u] = 8.0f;
  }
  __syncthreads();

  int lane = t & 63;
  int w = t >> 6;

  f32x4 zero4 = {0.f, 0.f, 0.f, 0.f};
  f32x4 acc[8];
  #pragma unroll
  for (int nt = 0; nt < 8; nt++) acc[nt] = zero4;

  // RBF constants: exp(-((d-mu_r)/1.25)^2) = exp2(-(d*C1 - (2+r*4/3)*C1)^2)
  // with C1 = 0.8*sqrt(log2 e)
  const float C1 = 0.96089792702916f;        // 0.8 * 1.2011224087864498
  const float DC = 1.28119723603888f;        // (4/3) * C1
  const float B0 = -1.92179585405832f;       // -2 * C1

  for (int c = 0; c < 4; c++) {
    // stage B chunk (16 KB) fragment-linear from global
    {
      const float4* src = (const float4*)(ws + WS_BPACK) + c * 1024;
      float4* dst = (float4*)(smem + SM_B);
      #pragma unroll
      for (int v = 0; v < 4; v++) dst[t + v * 256] = src[t + v * 256];
    }
    // fill A fragment-linear: [w(4)][s(2)][lane(64)][j(8)] bf16, as u32 pairs
    {
      unsigned* ap = (unsigned*)(smem + SM_A);
      #pragma unroll
      for (int v = 0; v < 8; v++) {
        int i2 = t + v * 256;
        int j2 = i2 & 3;
        int al = (i2 >> 2) & 63;
        int s = (i2 >> 8) & 1;
        int aw = (i2 >> 9) & 3;
        int m = aw * 16 + (al & 15);
        int k = c * 64 + s * 32 + (al >> 4) * 8 + j2 * 2;
        float d = s_dist[m * 17 + (k >> 4)];
        float rrf = (float)(k & 15);
        float base = fmaf(rrf, -DC, B0);
        float zs0 = fmaf(d, C1, base);
        float zs1 = zs0 - DC;
        float v0 = __builtin_exp2f(-zs0 * zs0);
        float v1 = __builtin_exp2f(-zs1 * zs1);
        ap[i2] = pk_bf16(v0, v1);
      }
    }
    __syncthreads();
    // MFMA: 2 k-steps x 8 n-tiles
    #pragma unroll
    for (int s = 0; s < 2; s++) {
      bf16x8 a = *(const bf16x8*)(smem + SM_A + ((w * 2 + s) * 64 + lane) * 16);
      #pragma unroll
      for (int nt = 0; nt < 8; nt++) {
        bf16x8 bfr = *(const bf16x8*)(smem + SM_B + ((nt * 2 + s) * 64 + lane) * 16);
        acc[nt] = __builtin_amdgcn_mfma_f32_16x16x32_bf16(a, bfr, acc[nt], 0, 0, 0);
      }
    }
    __syncthreads();
  }

  // epilogue: LN directly from accumulator layout.
  // acc[nt][r] = C[m][f], m = w*16 + quad*4 + r, f = nt*16 + col0
  int quad = lane >> 4;
  int col0 = lane & 15;
  #pragma unroll
  for (int r = 0; r < 4; r++) {
    int e = w * 16 + quad * 4 + r;
    bool live = (e < 60);
    int dp = live ? s_pos[e] : 0;
    const float* tp = Tpos + dp * 128;
    float vv[8];
    float s = 0.f, s2 = 0.f;
    #pragma unroll
    for (int nt = 0; nt < 8; nt++) {
      float x = acc[nt][r] + tp[nt * 16 + col0];
      vv[nt] = x;
      s += x;
      s2 += x * x;
    }
    #pragma unroll
    for (int off = 8; off; off >>= 1) {
      s += __shfl_xor(s, off, 16);
      s2 += __shfl_xor(s2, off, 16);
    }
    float mu = s * (1.0f / 128.0f);
    float var = s2 * (1.0f / 128.0f) - mu * mu;
    float inv = rsqrtf(var + 1e-5f);
    if (live) {
      int row = r0 + (e >= 30 ? 1 : 0);
      int kn = e - (e >= 30 ? 30 : 0);
      float* o = out + ((size_t)row * TOPK + kn) * 128;
      #pragma unroll
      for (int nt = 0; nt < 8; nt++) {
        int f = nt * 16 + col0;
        o[f] = (vv[nt] - mu) * inv * ln_g[f] + ln_b[f];
      }
    }
  }
}

// ---------------------------------------------------------------- launch
extern "C" void kernel_launch(void* const* d_in, const int* in_sizes, int n_in,
                              void* d_out, int out_size, void* d_ws, size_t ws_size,
                              hipStream_t stream) {
  const float* X      = (const float*)d_in[0];
  const float* mask   = (const float*)d_in[1];
  const int*   ridx   = (const int*)d_in[2];
  const int*   chain  = (const int*)d_in[3];
  const float* pe_w   = (const float*)d_in[4];
  const float* pe_b   = (const float*)d_in[5];
  const float* edge_w = (const float*)d_in[6];
  const float* ln_g   = (const float*)d_in[7];
  const float* ln_b   = (const float*)d_in[8];
  float* out = (float*)d_out;
  float* ws  = (float*)d_ws;

  hipLaunchKernelGGL(prep_kernel, dim3(129), dim3(256), 0, stream,
                     X, pe_w, pe_b, edge_w, ws);
  hipLaunchKernelGGL(topk_kernel, dim3(NROW), dim3(256), 0, stream,
                     ws, mask, (int*)(ws + WS_EIDX), out + (size_t)NEDGE * 128);
  hipLaunchKernelGGL(edge_kernel, dim3(NROW / 2), dim3(256), 0, stream,
                     X, ws, ridx, chain, ln_g, ln_b, out);
}

// Round 9
// 240.044 us; speedup vs baseline: 1.1712x; 1.0357x over previous
//
#include <hip/hip_runtime.h>
#include <cfloat>
#include <cstdint>

#define B_DIM 4
#define L_DIM 2048
#define NROW (B_DIM * L_DIM)      // 8192
#define TOPK 30
#define NEDGE (NROW * TOPK)       // 245760

// workspace layout (float offsets)
#define WS_CB    0                // 24576 floats: Cb[row][3]
#define WS_CX    24576            // 8192
#define WS_CY    32768            // 8192
#define WS_CZ    40960            // 8192
#define WS_TPOS  49152            // 8448:  Tpos[d][f], 66x128 fp32
#define WS_BPACK 57600            // 16384 floats = 32768 bf16, fragment-linear
#define WS_EIDX  73984            // 245760 ints

typedef __bf16 bf16x8 __attribute__((ext_vector_type(8)));
typedef __bf16 bf16x2 __attribute__((ext_vector_type(2)));
typedef float f32x4 __attribute__((ext_vector_type(4)));

static __device__ __forceinline__ unsigned short f2bf(float x) {
  unsigned u = __float_as_uint(x);
  unsigned r = (u + 0x7fffu + ((u >> 16) & 1u)) >> 16;
  return (unsigned short)r;
}

static __device__ __forceinline__ unsigned pk_bf16(float a, float b) {
#if __has_builtin(__builtin_amdgcn_cvt_pk_bf16_f32)
  union { bf16x2 v; unsigned u; } cv;
  cv.v = __builtin_amdgcn_cvt_pk_bf16_f32(a, b);
  return cv.u;
#else
  return (unsigned)f2bf(a) | ((unsigned)f2bf(b) << 16);
#endif
}

// Wave64 u32 min-reduce on the VALU only (no DS pipe): DPP row_shr
// 1,2,4,8 then row_bcast15 (rows 1,3) and row_bcast31 (rows 2,3);
// full reduction lands in lane 63, broadcast back via v_readlane.
// For MIN, invalid-source lanes returning old(=v) are the identity.
static __device__ __forceinline__ unsigned wave_min_u32_dpp(unsigned v) {
#if __has_builtin(__builtin_amdgcn_update_dpp) && __has_builtin(__builtin_amdgcn_readlane)
  int x = (int)v, t;
  t = __builtin_amdgcn_update_dpp(x, x, 0x111, 0xf, 0xf, false);  // row_shr:1
  x = ((unsigned)t < (unsigned)x) ? t : x;
  t = __builtin_amdgcn_update_dpp(x, x, 0x112, 0xf, 0xf, false);  // row_shr:2
  x = ((unsigned)t < (unsigned)x) ? t : x;
  t = __builtin_amdgcn_update_dpp(x, x, 0x114, 0xf, 0xf, false);  // row_shr:4
  x = ((unsigned)t < (unsigned)x) ? t : x;
  t = __builtin_amdgcn_update_dpp(x, x, 0x118, 0xf, 0xf, false);  // row_shr:8
  x = ((unsigned)t < (unsigned)x) ? t : x;
  t = __builtin_amdgcn_update_dpp(x, x, 0x142, 0xa, 0xf, false);  // row_bcast15
  x = ((unsigned)t < (unsigned)x) ? t : x;
  t = __builtin_amdgcn_update_dpp(x, x, 0x143, 0xc, 0xf, false);  // row_bcast31
  x = ((unsigned)t < (unsigned)x) ? t : x;
  return (unsigned)__builtin_amdgcn_readlane(x, 63);
#else
  unsigned mv = v;
  #pragma unroll
  for (int off = 32; off; off >>= 1) {
    unsigned o = __shfl_xor(mv, off);
    mv = o < mv ? o : mv;
  }
  return mv;
#endif
}

// ---------------------------------------------------------------- prep
__global__ void prep_kernel(const float* __restrict__ X,
                            const float* __restrict__ pe_w,
                            const float* __restrict__ pe_b,
                            const float* __restrict__ edge_w,
                            float* __restrict__ ws) {
  int tid = blockIdx.x * 256 + threadIdx.x;
  if (tid < NROW) {
    const float* Xr = X + (size_t)tid * 12;
    float nx = Xr[0], ny = Xr[1], nz = Xr[2];   // N
    float cx = Xr[3], cy = Xr[4], cz = Xr[5];   // C
    float ax = Xr[6], ay = Xr[7], az = Xr[8];   // Ca
    float bx = ax - nx, by = ay - ny, bz = az - nz;   // b = Ca - N
    float vx = cx - ax, vy = cy - ay, vz = cz - az;   // c = C - Ca
    float crx = by * vz - bz * vy;
    float cry = bz * vx - bx * vz;
    float crz = bx * vy - by * vx;
    ws[WS_CB + tid * 3 + 0] = -0.58273431f * crx + 0.56802827f * bx - 0.54067466f * vx + ax;
    ws[WS_CB + tid * 3 + 1] = -0.58273431f * cry + 0.56802827f * by - 0.54067466f * vy + ay;
    ws[WS_CB + tid * 3 + 2] = -0.58273431f * crz + 0.56802827f * bz - 0.54067466f * vz + az;
    ws[WS_CX + tid] = cx;
    ws[WS_CY + tid] = cy;
    ws[WS_CZ + tid] = cz;
  } else if (tid < NROW + 8448) {
    int t2 = tid - NROW;
    int d = t2 >> 7, f = t2 & 127;
    float s = 0.f;
    #pragma unroll
    for (int n = 0; n < 16; n++)
      s += edge_w[f * 272 + n] * (pe_w[n * 66 + d] + pe_b[n]);
    ws[WS_TPOS + t2] = s;
  } else if (tid < NROW + 8448 + 16384) {
    // Bpack: bf16 fragment-linear [c(4)][nt(8)][s(2)][lane(64)][j(8)] as u32 pairs
    int i2 = tid - NROW - 8448;
    int j2 = i2 & 3;
    int lane = (i2 >> 2) & 63;
    int s = (i2 >> 8) & 1;
    int nt = (i2 >> 9) & 7;
    int c = (i2 >> 12) & 3;
    int f = nt * 16 + (lane & 15);
    int k = c * 64 + s * 32 + (lane >> 4) * 8 + j2 * 2;
    float v0 = edge_w[f * 272 + 16 + k];
    float v1 = edge_w[f * 272 + 16 + k + 1];
    unsigned out = (unsigned)f2bf(v0) | ((unsigned)f2bf(v1) << 16);
    ((unsigned*)(ws + WS_BPACK))[i2] = out;
  }
}

// ---------------------------------------------------------------- top-k
// v8 (verified): tournament with DPP min-reduce, readlane broadcasts,
// register nxt-head, LDS spill queue, 4-run bitonic merge.
#define CAS64(a, b) { bool lt = (a) < (b); \
  unsigned long long lo = lt ? (a) : (b), hi = lt ? (b) : (a); (a) = lo; (b) = hi; }

__global__ void __launch_bounds__(256)
topk_kernel(const float* __restrict__ ws,
            const float* __restrict__ mask,
            int* __restrict__ eidx_out,
            float* __restrict__ idxf_out) {
  int row = blockIdx.x;
  int b = row >> 11;
  int li = row & 2047;
  int t = threadIdx.x;
  int lane = t & 63;
  int w = t >> 6;                  // wave 0..3, 512 elements each

  __shared__ float s_red[4];
  __shared__ unsigned long long s_cand[128];       // 4 runs x 32
  __shared__ unsigned long long s_q[4 * 6 * 64];   // per-wave spill: slots 2..7

  const float* Cx = ws + WS_CX + b * L_DIM;
  const float* Cy = ws + WS_CY + b * L_DIM;
  const float* Cz = ws + WS_CZ + b * L_DIM;

  float cix = Cx[li], ciy = Cy[li], ciz = Cz[li];
  float mi = mask[row];

  float dloc[8], m2l[8];
  float dmax = 0.f;
  #pragma unroll
  for (int i = 0; i < 8; i++) {
    int j = w * 512 + i * 64 + lane;
    float dx = Cx[j] - cix;
    float dy = Cy[j] - ciy;
    float dz = Cz[j] - ciz;
    float raw = sqrtf(dx * dx + dy * dy + dz * dz + 1e-6f);
    float m2 = mi * mask[b * L_DIM + j];
    float d = m2 * raw;
    dloc[i] = d;
    m2l[i] = m2;
    dmax = fmaxf(dmax, d);
  }
  #pragma unroll
  for (int off = 32; off; off >>= 1)
    dmax = fmaxf(dmax, __shfl_xor(dmax, off));
  if (lane == 0) s_red[w] = dmax;
  __syncthreads();
  dmax = fmaxf(fmaxf(s_red[0], s_red[1]), fmaxf(s_red[2], s_red[3]));

  unsigned long long key[8];
  #pragma unroll
  for (int i = 0; i < 8; i++) {
    float v = dloc[i] + (1.f - m2l[i]) * dmax;
    int j = w * 512 + i * 64 + lane;
    key[i] = ((unsigned long long)__float_as_uint(v) << 32) | (unsigned)j;
  }
  // sort 8 keys ascending (19-comparator network)
  CAS64(key[0], key[1]); CAS64(key[2], key[3]); CAS64(key[4], key[5]); CAS64(key[6], key[7]);
  CAS64(key[0], key[2]); CAS64(key[1], key[3]); CAS64(key[4], key[6]); CAS64(key[5], key[7]);
  CAS64(key[1], key[2]); CAS64(key[5], key[6]); CAS64(key[0], key[4]); CAS64(key[3], key[7]);
  CAS64(key[1], key[5]); CAS64(key[2], key[6]);
  CAS64(key[1], key[4]); CAS64(key[3], key[6]);
  CAS64(key[2], key[4]); CAS64(key[3], key[5]);
  CAS64(key[3], key[4]);

  // spill slots 2..7 to the private LDS queue (same-wave access only)
  #pragma unroll
  for (int s = 2; s < 8; s++)
    s_q[(w * 6 + (s - 2)) * 64 + lane] = key[s];

  unsigned cv = (unsigned)(key[0] >> 32);
  unsigned cj = (unsigned)key[0];
  unsigned long long nxt = key[1];   // next head, in-register
  int ptr = 0;                       // next spill slot (0..5), >=6 exhausted

  unsigned long long myout = ~0ull;

  for (int n = 0; n < TOPK; n++) {
    unsigned mv = wave_min_u32_dpp(cv);          // VALU-only reduce
    unsigned long long ball = __ballot(cv == mv);
    if (ball == 0) ball = 1;                     // unreachable if reduce ok
    unsigned wj;
    bool me;
    if (__popcll(ball) == 1) {     // unique winner (uniform branch, ~always)
      int wl = (int)__builtin_ctzll(ball);
#if __has_builtin(__builtin_amdgcn_readlane)
      wj = (unsigned)__builtin_amdgcn_readlane((int)cj, wl);
#else
      wj = (unsigned)__shfl((int)cj, wl);
#endif
      me = (lane == wl);
    } else {                       // exact tie-break: min index among tied
      unsigned tj = (cv == mv) ? cj : 0xffffffffu;
      unsigned mj = tj;
      #pragma unroll
      for (int off = 32; off; off >>= 1) {
        unsigned o = __shfl_xor(mj, off);
        mj = o < mj ? o : mj;
      }
      wj = mj;
      me = (cv == mv) && (cj == mj);
    }
    if (lane == n)
      myout = ((unsigned long long)mv << 32) | wj;
    if (me) {                      // pop: head <- nxt (register), refill nxt
      cv = (unsigned)(nxt >> 32);
      cj = (unsigned)nxt;
      nxt = (ptr < 6) ? s_q[(w * 6 + ptr) * 64 + lane] : ~0ull;
      ptr++;
    }
  }
  if (lane < 32)
    s_cand[w * 32 + lane] = (lane < TOPK) ? myout : ~0ull;
  __syncthreads();

  // wave 0: merge 4 sorted-32 runs via truncated bitonic merges
  if (w == 0) {
    unsigned long long c0 = s_cand[lane];
    unsigned long long c1 = s_cand[64 + lane];
    bool lowhalf = lane < 32;

    #define MERGE32(c) { \
      unsigned long long p = __shfl_xor((c), 63); \
      (c) = (c) < p ? (c) : p; \
      _Pragma("unroll") \
      for (int j = 16; j; j >>= 1) { \
        unsigned long long q = __shfl_xor((c), j); \
        bool up = (lane & j) == 0; \
        unsigned long long mn = (c) < q ? (c) : q; \
        unsigned long long mx = (c) < q ? q : (c); \
        (c) = up ? mn : mx; \
      } }

    MERGE32(c0); MERGE32(c1);
    c0 = lowhalf ? c0 : c1;
    MERGE32(c0);
    #undef MERGE32

    if (lane < TOPK) {
      int j = (int)(c0 & 0xffffffffull);
      eidx_out[row * TOPK + lane] = j;
      idxf_out[row * TOPK + lane] = (float)j;
    }
  }
}

// ---------------------------------------------------------------- edges
// v9: wave-local restructure.
//  - A-fragments computed directly into registers (the [aw=w][s][lane][j2]
//    remap makes each lane's A-fill output exactly its own MFMA fragment)
//    -> no A region in LDS, no A barrier.
//  - s_dist/s_pos are produced by threads 4e..4e+3 (wave e>>4) and read
//    only by wave e>>4 -> same-wave LDS, no barrier (round-2-verified).
//  - B double-buffered (2x16KB), chunk c+1 staged before MFMA(c):
//    load latency hides under MFMA + exp2 work. ONE barrier per chunk.
// atom-pair codes, 4 bits each, p=0..15 (0=N,1=C,2=Ca,3=Cb)
#define PA_BITS 0x2323203001113201ull
#define PB_BITS 0x3001112323203201ull

// smem layout (bytes): DIST 64x17 fp32 [0,4352) | POS [4352,4608) |
//                      B dbuf [4608, 4608+2*16384 = 37376)
#define SM_DIST 0
#define SM_POS  4352
#define SM_B    4608
#define SM_TOTAL 37376

__global__ void __launch_bounds__(256)
edge_kernel(const float* __restrict__ X,
            const float* __restrict__ ws,
            const int* __restrict__ ridx,
            const int* __restrict__ chain,
            const float* __restrict__ ln_g,
            const float* __restrict__ ln_b,
            float* __restrict__ out) {
  __shared__ __align__(16) char smem[SM_TOTAL];
  float* s_dist = (float*)(smem + SM_DIST);   // [e][17], p in 0..15
  int* s_pos = (int*)(smem + SM_POS);

  int t = threadIdx.x;
  int r0 = blockIdx.x * 2;
  const float* Cbw = ws + WS_CB;
  const float* Tpos = ws + WS_TPOS;
  const int* eidx = (const int*)(ws + WS_EIDX);

  // phase 0: per-edge distances + positional index (4 threads per edge;
  // edge e handled by threads 4e..4e+3 == wave e>>4, so all later reads
  // of s_dist/s_pos are same-wave).
  if (t < 240) {
    int e = t >> 2, q = t & 3;
    int row = r0 + (e >= 30 ? 1 : 0);
    int kn = e - (e >= 30 ? 30 : 0);
    int bb = row >> 11;
    int j = eidx[row * TOPK + kn];
    int jrow = bb * L_DIM + j;
    if (q == 0) {
      int off = ridx[row] - ridx[jrow];
      int same = (chain[row] == chain[jrow]);
      s_pos[e] = same ? min(max(off + 32, 0), 64) : 65;
    }
    const float4* Xi4 = (const float4*)(X + (size_t)row * 12);
    const float4* Xj4 = (const float4*)(X + (size_t)jrow * 12);
    float4 i0 = Xi4[0], i1 = Xi4[1];
    float4 j0 = Xj4[0], j1 = Xj4[1];
    float i2x = X[(size_t)row * 12 + 8];
    float j2x = X[(size_t)jrow * 12 + 8];
    float axi[4], ayi[4], azi[4], axj[4], ayj[4], azj[4];
    axi[0] = i0.x; ayi[0] = i0.y; azi[0] = i0.z;        // N
    axi[1] = i0.w; ayi[1] = i1.x; azi[1] = i1.y;        // C
    axi[2] = i1.z; ayi[2] = i1.w; azi[2] = i2x;         // Ca
    axi[3] = Cbw[row * 3 + 0]; ayi[3] = Cbw[row * 3 + 1]; azi[3] = Cbw[row * 3 + 2];
    axj[0] = j0.x; ayj[0] = j0.y; azj[0] = j0.z;
    axj[1] = j0.w; ayj[1] = j1.x; azj[1] = j1.y;
    axj[2] = j1.z; ayj[2] = j1.w; azj[2] = j2x;
    axj[3] = Cbw[jrow * 3 + 0]; ayj[3] = Cbw[jrow * 3 + 1]; azj[3] = Cbw[jrow * 3 + 2];
    #pragma unroll
    for (int u = 0; u < 4; u++) {
      int p = q * 4 + u;
      int a = (int)((PA_BITS >> (p * 4)) & 7);
      int bc = (int)((PB_BITS >> (p * 4)) & 7);
      float dx = axi[a] - axj[bc];
      float dy = ayi[a] - ayj[bc];
      float dz = azi[a] - azj[bc];
      s_dist[e * 17 + p] = sqrtf(dx * dx + dy * dy + dz * dz + 1e-6f);
    }
  } else {
    int t2 = t - 240;        // pad edges 60..63 (threads 240..255 = wave 3)
    int e = 60 + (t2 >> 2), q = t2 & 3;
    if (q == 0) s_pos[e] = 0;
    #pragma unroll
    for (int u = 0; u < 4; u++) s_dist[e * 17 + q * 4 + u] = 8.0f;
  }

  int lane = t & 63;
  int w = t >> 6;

  f32x4 zero4 = {0.f, 0.f, 0.f, 0.f};
  f32x4 acc[8];
  #pragma unroll
  for (int nt = 0; nt < 8; nt++) acc[nt] = zero4;

  // RBF constants: exp(-((d-mu_r)/1.25)^2) = exp2(-(d*C1 - (2+r*4/3)*C1)^2)
  const float C1 = 0.96089792702916f;        // 0.8 * 1.2011224087864498
  const float DC = 1.28119723603888f;        // (4/3) * C1
  const float B0 = -1.92179585405832f;       // -2 * C1

  // stage B chunk cc (16 KB) into buffer cc&1 (all 256 threads)
  #define STAGE(cc) { \
    const float4* src = (const float4*)(ws + WS_BPACK) + (cc) * 1024; \
    float4* dst = (float4*)(smem + SM_B + ((cc) & 1) * 16384); \
    _Pragma("unroll") \
    for (int v2 = 0; v2 < 4; v2++) dst[t + v2 * 256] = src[t + v2 * 256]; }

  // A-fragment for (chunk cc, k-step s) straight into registers.
  // Lane holds A[m = w*16+(lane&15)][k = cc*64+s*32+(lane>>4)*8 + j],
  // j = 0..7 -- exactly the mfma_16x16x32 A layout.
  #define MAKE_AFRAG(dstv, cc, ss) { \
    union { unsigned u[4]; bf16x8 v; } cvt; \
    _Pragma("unroll") \
    for (int j2 = 0; j2 < 4; j2++) { \
      int k = (cc) * 64 + (ss) * 32 + (lane >> 4) * 8 + j2 * 2; \
      float d = s_dist[(w * 16 + (lane & 15)) * 17 + (k >> 4)]; \
      float rrf = (float)(k & 15); \
      float base = fmaf(rrf, -DC, B0); \
      float zs0 = fmaf(d, C1, base); \
      float zs1 = zs0 - DC; \
      cvt.u[j2] = pk_bf16(__builtin_exp2f(-zs0 * zs0), \
                          __builtin_exp2f(-zs1 * zs1)); \
    } \
    (dstv) = cvt.v; }

  bf16x8 af0, af1;
  STAGE(0);                      // B0 loads in flight...
  MAKE_AFRAG(af0, 0, 0);         // ...hidden under exp2 work (same-wave dist)
  MAKE_AFRAG(af1, 0, 1);
  __syncthreads();               // [1] B0 visible

  #pragma unroll
  for (int c = 0; c < 4; c++) {
    if (c < 3) STAGE(c + 1);     // prefetch next chunk into other buffer
    #pragma unroll
    for (int s = 0; s < 2; s++) {
      bf16x8 a = (s == 0) ? af0 : af1;
      #pragma unroll
      for (int nt = 0; nt < 8; nt++) {
        bf16x8 bfr = *(const bf16x8*)(smem + SM_B + (c & 1) * 16384 +
                                      ((nt * 2 + s) * 64 + lane) * 16);
        acc[nt] = __builtin_amdgcn_mfma_f32_16x16x32_bf16(a, bfr, acc[nt], 0, 0, 0);
      }
    }
    if (c < 3) {
      MAKE_AFRAG(af0, c + 1, 0);
      MAKE_AFRAG(af1, c + 1, 1);
      __syncthreads();           // next B buffer complete; prev fully read
    }
  }
  #undef STAGE
  #undef MAKE_AFRAG

  // epilogue: LN directly from accumulator layout.
  // acc[nt][r] = C[m][f], m = w*16 + quad*4 + r, f = nt*16 + col0
  int quad = lane >> 4;
  int col0 = lane & 15;
  #pragma unroll
  for (int r = 0; r < 4; r++) {
    int e = w * 16 + quad * 4 + r;          // in [16w, 16w+16) -> same-wave s_pos
    bool live = (e < 60);
    int dp = live ? s_pos[e] : 0;
    const float* tp = Tpos + dp * 128;
    float vv[8];
    float s = 0.f, s2 = 0.f;
    #pragma unroll
    for (int nt = 0; nt < 8; nt++) {
      float x = acc[nt][r] + tp[nt * 16 + col0];
      vv[nt] = x;
      s += x;
      s2 += x * x;
    }
    #pragma unroll
    for (int off = 8; off; off >>= 1) {
      s += __shfl_xor(s, off, 16);
      s2 += __shfl_xor(s2, off, 16);
    }
    float mu = s * (1.0f / 128.0f);
    float var = s2 * (1.0f / 128.0f) - mu * mu;
    float inv = rsqrtf(var + 1e-5f);
    if (live) {
      int row = r0 + (e >= 30 ? 1 : 0);
      int kn = e - (e >= 30 ? 30 : 0);
      float* o = out + ((size_t)row * TOPK + kn) * 128;
      #pragma unroll
      for (int nt = 0; nt < 8; nt++) {
        int f = nt * 16 + col0;
        o[f] = (vv[nt] - mu) * inv * ln_g[f] + ln_b[f];
      }
    }
  }
}

// ---------------------------------------------------------------- launch
extern "C" void kernel_launch(void* const* d_in, const int* in_sizes, int n_in,
                              void* d_out, int out_size, void* d_ws, size_t ws_size,
                              hipStream_t stream) {
  const float* X      = (const float*)d_in[0];
  const float* mask   = (const float*)d_in[1];
  const int*   ridx   = (const int*)d_in[2];
  const int*   chain  = (const int*)d_in[3];
  const float* pe_w   = (const float*)d_in[4];
  const float* pe_b   = (const float*)d_in[5];
  const float* edge_w = (const float*)d_in[6];
  const float* ln_g   = (const float*)d_in[7];
  const float* ln_b   = (const float*)d_in[8];
  float* out = (float*)d_out;
  float* ws  = (float*)d_ws;

  hipLaunchKernelGGL(prep_kernel, dim3(129), dim3(256), 0, stream,
                     X, pe_w, pe_b, edge_w, ws);
  hipLaunchKernelGGL(topk_kernel, dim3(NROW), dim3(256), 0, stream,
                     ws, mask, (int*)(ws + WS_EIDX), out + (size_t)NEDGE * 128);
  hipLaunchKernelGGL(edge_kernel, dim3(NROW / 2), dim3(256), 0, stream,
                     X, ws, ridx, chain, ln_g, ln_b, out);
}

// Round 10
// 239.698 us; speedup vs baseline: 1.1729x; 1.0014x over previous
//
#include <hip/hip_runtime.h>
#include <cfloat>
#include <cstdint>

#define B_DIM 4
#define L_DIM 2048
#define NROW (B_DIM * L_DIM)      // 8192
#define TOPK 30
#define NEDGE (NROW * TOPK)       // 245760

// workspace layout (float offsets)
#define WS_CB    0                // 24576 floats: Cb[row][3]
#define WS_TPOS  49152            // 8448:  Tpos[d][f], 66x128 fp32
#define WS_BPACK 57600            // 16384 floats = 32768 bf16, fragment-linear
#define WS_EIDX  73984            // 245760 ints

typedef __bf16 bf16x8 __attribute__((ext_vector_type(8)));
typedef __bf16 bf16x2 __attribute__((ext_vector_type(2)));
typedef float f32x4 __attribute__((ext_vector_type(4)));

static __device__ __forceinline__ unsigned short f2bf(float x) {
  unsigned u = __float_as_uint(x);
  unsigned r = (u + 0x7fffu + ((u >> 16) & 1u)) >> 16;
  return (unsigned short)r;
}

static __device__ __forceinline__ unsigned pk_bf16(float a, float b) {
#if __has_builtin(__builtin_amdgcn_cvt_pk_bf16_f32)
  union { bf16x2 v; unsigned u; } cv;
  cv.v = __builtin_amdgcn_cvt_pk_bf16_f32(a, b);
  return cv.u;
#else
  return (unsigned)f2bf(a) | ((unsigned)f2bf(b) << 16);
#endif
}

// Wave64 u32 min-reduce on the VALU only (no DS pipe): DPP row_shr
// 1,2,4,8 then row_bcast15 (rows 1,3) and row_bcast31 (rows 2,3);
// full reduction lands in lane 63, broadcast back via v_readlane.
// For MIN, invalid-source lanes returning old(=v) are the identity.
static __device__ __forceinline__ unsigned wave_min_u32_dpp(unsigned v) {
#if __has_builtin(__builtin_amdgcn_update_dpp) && __has_builtin(__builtin_amdgcn_readlane)
  int x = (int)v, t;
  t = __builtin_amdgcn_update_dpp(x, x, 0x111, 0xf, 0xf, false);  // row_shr:1
  x = ((unsigned)t < (unsigned)x) ? t : x;
  t = __builtin_amdgcn_update_dpp(x, x, 0x112, 0xf, 0xf, false);  // row_shr:2
  x = ((unsigned)t < (unsigned)x) ? t : x;
  t = __builtin_amdgcn_update_dpp(x, x, 0x114, 0xf, 0xf, false);  // row_shr:4
  x = ((unsigned)t < (unsigned)x) ? t : x;
  t = __builtin_amdgcn_update_dpp(x, x, 0x118, 0xf, 0xf, false);  // row_shr:8
  x = ((unsigned)t < (unsigned)x) ? t : x;
  t = __builtin_amdgcn_update_dpp(x, x, 0x142, 0xa, 0xf, false);  // row_bcast15
  x = ((unsigned)t < (unsigned)x) ? t : x;
  t = __builtin_amdgcn_update_dpp(x, x, 0x143, 0xc, 0xf, false);  // row_bcast31
  x = ((unsigned)t < (unsigned)x) ? t : x;
  return (unsigned)__builtin_amdgcn_readlane(x, 63);
#else
  unsigned mv = v;
  #pragma unroll
  for (int off = 32; off; off >>= 1) {
    unsigned o = __shfl_xor(mv, off);
    mv = o < mv ? o : mv;
  }
  return mv;
#endif
}

// ---------------------------------------------------------------- fused
// v10: prep fused into the topk dispatch as extra blocks (grid NROW+129).
// topk blocks read C-atom coords DIRECTLY from X (L2-resident), removing
// the prep->topk dependency; prep blocks (blockIdx >= NROW) write only
// Cb/Tpos/Bpack, read only by the later edge dispatch. No shared state,
// no barriers in the prep path -> safe to co-dispatch.
// topk body: round-8-verified tournament (DPP min-reduce, readlane
// broadcasts, register nxt-head, LDS spill queue, 4-run bitonic merge).
#define CAS64(a, b) { bool lt = (a) < (b); \
  unsigned long long lo = lt ? (a) : (b), hi = lt ? (b) : (a); (a) = lo; (b) = hi; }

__global__ void __launch_bounds__(256)
topk_kernel(const float* __restrict__ X,
            const float* __restrict__ mask,
            const float* __restrict__ pe_w,
            const float* __restrict__ pe_b,
            const float* __restrict__ edge_w,
            float* __restrict__ ws,
            int* __restrict__ eidx_out,
            float* __restrict__ idxf_out) {
  int t = threadIdx.x;

  if (blockIdx.x >= NROW) {
    // ---- prep path (129 blocks x 256 = 33024 work items) ----
    int tid = (blockIdx.x - NROW) * 256 + t;
    if (tid < NROW) {
      const float* Xr = X + (size_t)tid * 12;
      float nx = Xr[0], ny = Xr[1], nz = Xr[2];   // N
      float cx = Xr[3], cy = Xr[4], cz = Xr[5];   // C
      float ax = Xr[6], ay = Xr[7], az = Xr[8];   // Ca
      float bx = ax - nx, by = ay - ny, bz = az - nz;   // b = Ca - N
      float vx = cx - ax, vy = cy - ay, vz = cz - az;   // c = C - Ca
      float crx = by * vz - bz * vy;
      float cry = bz * vx - bx * vz;
      float crz = bx * vy - by * vx;
      ws[WS_CB + tid * 3 + 0] = -0.58273431f * crx + 0.56802827f * bx - 0.54067466f * vx + ax;
      ws[WS_CB + tid * 3 + 1] = -0.58273431f * cry + 0.56802827f * by - 0.54067466f * vy + ay;
      ws[WS_CB + tid * 3 + 2] = -0.58273431f * crz + 0.56802827f * bz - 0.54067466f * vz + az;
    } else if (tid < NROW + 8448) {
      int t2 = tid - NROW;
      int d = t2 >> 7, f = t2 & 127;
      float s = 0.f;
      #pragma unroll
      for (int n = 0; n < 16; n++)
        s += edge_w[f * 272 + n] * (pe_w[n * 66 + d] + pe_b[n]);
      ws[WS_TPOS + t2] = s;
    } else if (tid < NROW + 8448 + 16384) {
      // Bpack: bf16 fragment-linear [c(4)][nt(8)][s(2)][lane(64)][j(8)] as u32 pairs
      int i2 = tid - NROW - 8448;
      int j2 = i2 & 3;
      int lane = (i2 >> 2) & 63;
      int s = (i2 >> 8) & 1;
      int nt = (i2 >> 9) & 7;
      int c = (i2 >> 12) & 3;
      int f = nt * 16 + (lane & 15);
      int k = c * 64 + s * 32 + (lane >> 4) * 8 + j2 * 2;
      float v0 = edge_w[f * 272 + 16 + k];
      float v1 = edge_w[f * 272 + 16 + k + 1];
      unsigned o = (unsigned)f2bf(v0) | ((unsigned)f2bf(v1) << 16);
      ((unsigned*)(ws + WS_BPACK))[i2] = o;
    }
    return;
  }

  // ---- topk path ----
  int row = blockIdx.x;
  int b = row >> 11;
  int lane = t & 63;
  int w = t >> 6;                  // wave 0..3, 512 elements each

  __shared__ float s_red[4];
  __shared__ unsigned long long s_cand[128];       // 4 runs x 32
  __shared__ unsigned long long s_q[4 * 6 * 64];   // per-wave spill: slots 2..7

  const float* Xb = X + (size_t)b * L_DIM * 12;

  float cix = X[(size_t)row * 12 + 3];
  float ciy = X[(size_t)row * 12 + 4];
  float ciz = X[(size_t)row * 12 + 5];
  float mi = mask[row];

  float dloc[8], m2l[8];
  float dmax = 0.f;
  #pragma unroll
  for (int i = 0; i < 8; i++) {
    int j = w * 512 + i * 64 + lane;
    const float* xj = Xb + (size_t)j * 12;
    float dx = xj[3] - cix;
    float dy = xj[4] - ciy;
    float dz = xj[5] - ciz;
    float raw = sqrtf(dx * dx + dy * dy + dz * dz + 1e-6f);
    float m2 = mi * mask[b * L_DIM + j];
    float d = m2 * raw;
    dloc[i] = d;
    m2l[i] = m2;
    dmax = fmaxf(dmax, d);
  }
  #pragma unroll
  for (int off = 32; off; off >>= 1)
    dmax = fmaxf(dmax, __shfl_xor(dmax, off));
  if (lane == 0) s_red[w] = dmax;
  __syncthreads();
  dmax = fmaxf(fmaxf(s_red[0], s_red[1]), fmaxf(s_red[2], s_red[3]));

  unsigned long long key[8];
  #pragma unroll
  for (int i = 0; i < 8; i++) {
    float v = dloc[i] + (1.f - m2l[i]) * dmax;
    int j = w * 512 + i * 64 + lane;
    key[i] = ((unsigned long long)__float_as_uint(v) << 32) | (unsigned)j;
  }
  // sort 8 keys ascending (19-comparator network)
  CAS64(key[0], key[1]); CAS64(key[2], key[3]); CAS64(key[4], key[5]); CAS64(key[6], key[7]);
  CAS64(key[0], key[2]); CAS64(key[1], key[3]); CAS64(key[4], key[6]); CAS64(key[5], key[7]);
  CAS64(key[1], key[2]); CAS64(key[5], key[6]); CAS64(key[0], key[4]); CAS64(key[3], key[7]);
  CAS64(key[1], key[5]); CAS64(key[2], key[6]);
  CAS64(key[1], key[4]); CAS64(key[3], key[6]);
  CAS64(key[2], key[4]); CAS64(key[3], key[5]);
  CAS64(key[3], key[4]);

  // spill slots 2..7 to the private LDS queue (same-wave access only)
  #pragma unroll
  for (int s = 2; s < 8; s++)
    s_q[(w * 6 + (s - 2)) * 64 + lane] = key[s];

  unsigned cv = (unsigned)(key[0] >> 32);
  unsigned cj = (unsigned)key[0];
  unsigned long long nxt = key[1];   // next head, in-register
  int ptr = 0;                       // next spill slot (0..5), >=6 exhausted

  unsigned long long myout = ~0ull;

  for (int n = 0; n < TOPK; n++) {
    unsigned mv = wave_min_u32_dpp(cv);          // VALU-only reduce
    unsigned long long ball = __ballot(cv == mv);
    if (ball == 0) ball = 1;                     // unreachable if reduce ok
    unsigned wj;
    bool me;
    if (__popcll(ball) == 1) {     // unique winner (uniform branch, ~always)
      int wl = (int)__builtin_ctzll(ball);
#if __has_builtin(__builtin_amdgcn_readlane)
      wj = (unsigned)__builtin_amdgcn_readlane((int)cj, wl);
#else
      wj = (unsigned)__shfl((int)cj, wl);
#endif
      me = (lane == wl);
    } else {                       // exact tie-break: min index among tied
      unsigned tj = (cv == mv) ? cj : 0xffffffffu;
      unsigned mj = tj;
      #pragma unroll
      for (int off = 32; off; off >>= 1) {
        unsigned o = __shfl_xor(mj, off);
        mj = o < mj ? o : mj;
      }
      wj = mj;
      me = (cv == mv) && (cj == mj);
    }
    if (lane == n)
      myout = ((unsigned long long)mv << 32) | wj;
    if (me) {                      // pop: head <- nxt (register), refill nxt
      cv = (unsigned)(nxt >> 32);
      cj = (unsigned)nxt;
      nxt = (ptr < 6) ? s_q[(w * 6 + ptr) * 64 + lane] : ~0ull;
      ptr++;
    }
  }
  if (lane < 32)
    s_cand[w * 32 + lane] = (lane < TOPK) ? myout : ~0ull;
  __syncthreads();

  // wave 0: merge 4 sorted-32 runs via truncated bitonic merges
  if (w == 0) {
    unsigned long long c0 = s_cand[lane];
    unsigned long long c1 = s_cand[64 + lane];
    bool lowhalf = lane < 32;

    #define MERGE32(c) { \
      unsigned long long p = __shfl_xor((c), 63); \
      (c) = (c) < p ? (c) : p; \
      _Pragma("unroll") \
      for (int j = 16; j; j >>= 1) { \
        unsigned long long q = __shfl_xor((c), j); \
        bool up = (lane & j) == 0; \
        unsigned long long mn = (c) < q ? (c) : q; \
        unsigned long long mx = (c) < q ? q : (c); \
        (c) = up ? mn : mx; \
      } }

    MERGE32(c0); MERGE32(c1);
    c0 = lowhalf ? c0 : c1;
    MERGE32(c0);
    #undef MERGE32

    if (lane < TOPK) {
      int j = (int)(c0 & 0xffffffffull);
      eidx_out[row * TOPK + lane] = j;
      idxf_out[row * TOPK + lane] = (float)j;
    }
  }
}

// ---------------------------------------------------------------- edges
// v9 (verified): wave-local A-fragments in registers, same-wave s_dist/
// s_pos (no barrier), B double-buffered with prefetch, 1 barrier/chunk.
// atom-pair codes, 4 bits each, p=0..15 (0=N,1=C,2=Ca,3=Cb)
#define PA_BITS 0x2323203001113201ull
#define PB_BITS 0x3001112323203201ull

// smem layout (bytes): DIST 64x17 fp32 [0,4352) | POS [4352,4608) |
//                      B dbuf [4608, 4608+2*16384 = 37376)
#define SM_DIST 0
#define SM_POS  4352
#define SM_B    4608
#define SM_TOTAL 37376

__global__ void __launch_bounds__(256)
edge_kernel(const float* __restrict__ X,
            const float* __restrict__ ws,
            const int* __restrict__ ridx,
            const int* __restrict__ chain,
            const float* __restrict__ ln_g,
            const float* __restrict__ ln_b,
            float* __restrict__ out) {
  __shared__ __align__(16) char smem[SM_TOTAL];
  float* s_dist = (float*)(smem + SM_DIST);   // [e][17], p in 0..15
  int* s_pos = (int*)(smem + SM_POS);

  int t = threadIdx.x;
  int r0 = blockIdx.x * 2;
  const float* Cbw = ws + WS_CB;
  const float* Tpos = ws + WS_TPOS;
  const int* eidx = (const int*)(ws + WS_EIDX);

  // phase 0: per-edge distances + positional index (4 threads per edge;
  // edge e handled by threads 4e..4e+3 == wave e>>4, so all later reads
  // of s_dist/s_pos are same-wave).
  if (t < 240) {
    int e = t >> 2, q = t & 3;
    int row = r0 + (e >= 30 ? 1 : 0);
    int kn = e - (e >= 30 ? 30 : 0);
    int bb = row >> 11;
    int j = eidx[row * TOPK + kn];
    int jrow = bb * L_DIM + j;
    if (q == 0) {
      int off = ridx[row] - ridx[jrow];
      int same = (chain[row] == chain[jrow]);
      s_pos[e] = same ? min(max(off + 32, 0), 64) : 65;
    }
    const float4* Xi4 = (const float4*)(X + (size_t)row * 12);
    const float4* Xj4 = (const float4*)(X + (size_t)jrow * 12);
    float4 i0 = Xi4[0], i1 = Xi4[1];
    float4 j0 = Xj4[0], j1 = Xj4[1];
    float i2x = X[(size_t)row * 12 + 8];
    float j2x = X[(size_t)jrow * 12 + 8];
    float axi[4], ayi[4], azi[4], axj[4], ayj[4], azj[4];
    axi[0] = i0.x; ayi[0] = i0.y; azi[0] = i0.z;        // N
    axi[1] = i0.w; ayi[1] = i1.x; azi[1] = i1.y;        // C
    axi[2] = i1.z; ayi[2] = i1.w; azi[2] = i2x;         // Ca
    axi[3] = Cbw[row * 3 + 0]; ayi[3] = Cbw[row * 3 + 1]; azi[3] = Cbw[row * 3 + 2];
    axj[0] = j0.x; ayj[0] = j0.y; azj[0] = j0.z;
    axj[1] = j0.w; ayj[1] = j1.x; azj[1] = j1.y;
    axj[2] = j1.z; ayj[2] = j1.w; azj[2] = j2x;
    axj[3] = Cbw[jrow * 3 + 0]; ayj[3] = Cbw[jrow * 3 + 1]; azj[3] = Cbw[jrow * 3 + 2];
    #pragma unroll
    for (int u = 0; u < 4; u++) {
      int p = q * 4 + u;
      int a = (int)((PA_BITS >> (p * 4)) & 7);
      int bc = (int)((PB_BITS >> (p * 4)) & 7);
      float dx = axi[a] - axj[bc];
      float dy = ayi[a] - ayj[bc];
      float dz = azi[a] - azj[bc];
      s_dist[e * 17 + p] = sqrtf(dx * dx + dy * dy + dz * dz + 1e-6f);
    }
  } else {
    int t2 = t - 240;        // pad edges 60..63 (threads 240..255 = wave 3)
    int e = 60 + (t2 >> 2), q = t2 & 3;
    if (q == 0) s_pos[e] = 0;
    #pragma unroll
    for (int u = 0; u < 4; u++) s_dist[e * 17 + q * 4 + u] = 8.0f;
  }

  int lane = t & 63;
  int w = t >> 6;

  f32x4 zero4 = {0.f, 0.f, 0.f, 0.f};
  f32x4 acc[8];
  #pragma unroll
  for (int nt = 0; nt < 8; nt++) acc[nt] = zero4;

  // RBF constants: exp(-((d-mu_r)/1.25)^2) = exp2(-(d*C1 - (2+r*4/3)*C1)^2)
  const float C1 = 0.96089792702916f;        // 0.8 * 1.2011224087864498
  const float DC = 1.28119723603888f;        // (4/3) * C1
  const float B0 = -1.92179585405832f;       // -2 * C1

  // stage B chunk cc (16 KB) into buffer cc&1 (all 256 threads)
  #define STAGE(cc) { \
    const float4* src = (const float4*)(ws + WS_BPACK) + (cc) * 1024; \
    float4* dst = (float4*)(smem + SM_B + ((cc) & 1) * 16384); \
    _Pragma("unroll") \
    for (int v2 = 0; v2 < 4; v2++) dst[t + v2 * 256] = src[t + v2 * 256]; }

  // A-fragment for (chunk cc, k-step s) straight into registers.
  #define MAKE_AFRAG(dstv, cc, ss) { \
    union { unsigned u[4]; bf16x8 v; } cvt; \
    _Pragma("unroll") \
    for (int j2 = 0; j2 < 4; j2++) { \
      int k = (cc) * 64 + (ss) * 32 + (lane >> 4) * 8 + j2 * 2; \
      float d = s_dist[(w * 16 + (lane & 15)) * 17 + (k >> 4)]; \
      float rrf = (float)(k & 15); \
      float base = fmaf(rrf, -DC, B0); \
      float zs0 = fmaf(d, C1, base); \
      float zs1 = zs0 - DC; \
      cvt.u[j2] = pk_bf16(__builtin_exp2f(-zs0 * zs0), \
                          __builtin_exp2f(-zs1 * zs1)); \
    } \
    (dstv) = cvt.v; }

  bf16x8 af0, af1;
  STAGE(0);                      // B0 loads in flight...
  MAKE_AFRAG(af0, 0, 0);         // ...hidden under exp2 work (same-wave dist)
  MAKE_AFRAG(af1, 0, 1);
  __syncthreads();               // [1] B0 visible

  #pragma unroll
  for (int c = 0; c < 4; c++) {
    if (c < 3) STAGE(c + 1);     // prefetch next chunk into other buffer
    #pragma unroll
    for (int s = 0; s < 2; s++) {
      bf16x8 a = (s == 0) ? af0 : af1;
      #pragma unroll
      for (int nt = 0; nt < 8; nt++) {
        bf16x8 bfr = *(const bf16x8*)(smem + SM_B + (c & 1) * 16384 +
                                      ((nt * 2 + s) * 64 + lane) * 16);
        acc[nt] = __builtin_amdgcn_mfma_f32_16x16x32_bf16(a, bfr, acc[nt], 0, 0, 0);
      }
    }
    if (c < 3) {
      MAKE_AFRAG(af0, c + 1, 0);
      MAKE_AFRAG(af1, c + 1, 1);
      __syncthreads();           // next B buffer complete; prev fully read
    }
  }
  #undef STAGE
  #undef MAKE_AFRAG

  // epilogue: LN directly from accumulator layout.
  // acc[nt][r] = C[m][f], m = w*16 + quad*4 + r, f = nt*16 + col0
  int quad = lane >> 4;
  int col0 = lane & 15;
  #pragma unroll
  for (int r = 0; r < 4; r++) {
    int e = w * 16 + quad * 4 + r;          // in [16w, 16w+16) -> same-wave s_pos
    bool live = (e < 60);
    int dp = live ? s_pos[e] : 0;
    const float* tp = Tpos + dp * 128;
    float vv[8];
    float s = 0.f, s2 = 0.f;
    #pragma unroll
    for (int nt = 0; nt < 8; nt++) {
      float x = acc[nt][r] + tp[nt * 16 + col0];
      vv[nt] = x;
      s += x;
      s2 += x * x;
    }
    #pragma unroll
    for (int off = 8; off; off >>= 1) {
      s += __shfl_xor(s, off, 16);
      s2 += __shfl_xor(s2, off, 16);
    }
    float mu = s * (1.0f / 128.0f);
    float var = s2 * (1.0f / 128.0f) - mu * mu;
    float inv = rsqrtf(var + 1e-5f);
    if (live) {
      int row = r0 + (e >= 30 ? 1 : 0);
      int kn = e - (e >= 30 ? 30 : 0);
      float* o = out + ((size_t)row * TOPK + kn) * 128;
      #pragma unroll
      for (int nt = 0; nt < 8; nt++) {
        int f = nt * 16 + col0;
        o[f] = (vv[nt] - mu) * inv * ln_g[f] + ln_b[f];
      }
    }
  }
}

// ---------------------------------------------------------------- launch
extern "C" void kernel_launch(void* const* d_in, const int* in_sizes, int n_in,
                              void* d_out, int out_size, void* d_ws, size_t ws_size,
                              hipStream_t stream) {
  const float* X      = (const float*)d_in[0];
  const float* mask   = (const float*)d_in[1];
  const int*   ridx   = (const int*)d_in[2];
  const int*   chain  = (const int*)d_in[3];
  const float* pe_w   = (const float*)d_in[4];
  const float* pe_b   = (const float*)d_in[5];
  const float* edge_w = (const float*)d_in[6];
  const float* ln_g   = (const float*)d_in[7];
  const float* ln_b   = (const float*)d_in[8];
  float* out = (float*)d_out;
  float* ws  = (float*)d_ws;

  hipLaunchKernelGGL(topk_kernel, dim3(NROW + 129), dim3(256), 0, stream,
                     X, mask, pe_w, pe_b, edge_w, ws,
                     (int*)(ws + WS_EIDX), out + (size_t)NEDGE * 128);
  hipLaunchKernelGGL(edge_kernel, dim3(NROW / 2), dim3(256), 0, stream,
                     X, ws, ridx, chain, ln_g, ln_b, out);
}